// Round 7
// baseline (369.864 us; speedup 1.0000x reference)
//
#include <hip/hip_runtime.h>
#include <hip/hip_bf16.h>

// MinGRU forward: z=sigmoid(xWz^T), h~=xWh^T, a=1-z+1e-8, b=z*h~, scan h=a*h+b.
// B=4 T=4096 D=1024.
// R10: R9 single-pass fused GEMM+scan (decoupled lookback), made deadlock-free.
// R9 hung: its chain ordering relied on HW dispatch order == flat wg id, which
// HIP does NOT guarantee (guide §6 G16). Fix (rocPRIM-style): TICKET-ORDERED
// virtual block id -- vbid = atomicAdd(ticket)&1023 at block entry; chains key
// on vbid. A block spins only on lower-vbid blocks, which by construction have
// STARTED (took earlier tickets) and publish flag=1 with no upstream spin =>
// no circular wait under any dispatch/scheduling order. &1023 + idempotent
// flag/inc values keep rocprof dispatch-replay safe. Ticket+flags zeroed by
// convert block 0 (stream-ordered). Scan algebra identical to R9:
//   pass A: per-chunk (16-row) affine aggregates via q-lane shuffle scan
//   spine:  publish block agg (flag=1) -> lookback (agg/inclusive) ->
//           publish inclusive (flag=2) -> 8 chunk Hstarts in LDS
//   pass B: recompute gate from acc regs, out = Apre*Hstart + Bpre (final).
// Tail kernels (a_ws/b_out round-trip, pass2, pass3; ~160MB + 2 dispatches)
// are deleted. K-loop = verified R8 structure (BK=64 dual-acc, MfmaUtil~31).

typedef __bf16 bf16x8 __attribute__((ext_vector_type(8)));
typedef float  f32x4  __attribute__((ext_vector_type(4)));

#define BSZ 4
#define TSZ 4096
#define DSZ 1024
#define MSZ (BSZ*TSZ)      // 16384 rows
#define CH  16             // scan chunk length
#define NC  (TSZ/CH)       // 256 chunks per sequence
#define CPB 32             // chain length in blocks (4096 rows / 128)
#define NBLK 1024          // total gemm blocks (128 x-tiles * 8 y-tiles)

__device__ __forceinline__ void gload_lds16(const __bf16* g, __bf16* l) {
  __builtin_amdgcn_global_load_lds(
      (const __attribute__((address_space(1))) void*)g,
      (__attribute__((address_space(3))) void*)l, 16, 0, 0);
}

// ---------------- conversion: fp32 row-major -> bf16 fragment-tiled ----------------
// tiled layout: [rowblk][kblk:32][i:8][l:64][j:8] where
//   row = rowblk*128 + i*16 + (l&15), k = kblk*32 + (l>>4)*8 + j
// Block 0 additionally zeroes the spine flags + ticket (ctrl[0..1024]);
// stream order guarantees completion before gemm_scan launches.
__global__ void convert_tile_kernel(const float* __restrict__ X,
                                    const float* __restrict__ Wz,
                                    const float* __restrict__ Wh,
                                    __bf16* __restrict__ Xc,
                                    __bf16* __restrict__ Wzc,
                                    __bf16* __restrict__ Whc,
                                    int* __restrict__ ctrl)
{
  const int bx = blockIdx.x;
  if (bx == 0) {
    #pragma unroll
    for (int k = 0; k < 4; ++k) ctrl[k*256 + threadIdx.x] = 0;
    if (threadIdx.x == 0) ctrl[NBLK] = 0;      // ticket
  }
  const float* src; __bf16* dst; int gid;
  if (bx < 8192)      { src = X;  dst = Xc;  gid =  bx        *256 + threadIdx.x; }
  else if (bx < 8704) { src = Wz; dst = Wzc; gid = (bx - 8192)*256 + threadIdx.x; }
  else                { src = Wh; dst = Whc; gid = (bx - 8704)*256 + threadIdx.x; }
  const int l    = gid & 63;
  const int i    = (gid >> 6) & 7;
  const int kblk = (gid >> 9) & 31;
  const int rblk = gid >> 14;
  const int row  = rblk*128 + i*16 + (l & 15);
  const int col  = kblk*32 + (l >> 4)*8;
  const float* g = src + (size_t)row*DSZ + col;
  float4 v0 = *(const float4*)g;
  float4 v1 = *(const float4*)(g + 4);
  bf16x8 p;
  p[0]=(__bf16)v0.x; p[1]=(__bf16)v0.y; p[2]=(__bf16)v0.z; p[3]=(__bf16)v0.w;
  p[4]=(__bf16)v1.x; p[5]=(__bf16)v1.y; p[6]=(__bf16)v1.z; p[7]=(__bf16)v1.w;
  *(bf16x8*)(dst + (size_t)gid*8) = p;
}

// ---------------- fused GEMM + gate + full scan + final output ----------------
// block tile 128(M) x 128(N), BK=64; 256 threads = 4 waves in 2x2, each 64x64.
__global__ __launch_bounds__(256, 2) void gemm_scan_kernel(
    const __bf16* __restrict__ Xc,  const __bf16* __restrict__ Wzc,
    const __bf16* __restrict__ Whc,
    const float* __restrict__ bz, const float* __restrict__ bh,
    float* __restrict__ out,
    float* aggA, float* aggB, float* incA, float* incB, int* ctrl)
{
  __shared__ __align__(16) __bf16 As [8192];
  __shared__ __align__(16) __bf16 Bzs[8192];
  __shared__ __align__(16) __bf16 Bhs[8192];
  __shared__ int vbid_s;

  const int tid  = threadIdx.x;
  // ---- ticket: dispatch-order-independent chain position ----
  if (tid == 0)
    vbid_s = __hip_atomic_fetch_add(&ctrl[NBLK], 1, __ATOMIC_RELAXED,
                                    __HIP_MEMORY_SCOPE_AGENT) & (NBLK - 1);
  __syncthreads();
  const int vbid = vbid_s;
  const int bx = vbid & 127;           // M tile (chain position)
  const int by = vbid >> 7;            // N tile

  const int lane = tid & 63;
  const int wv   = tid >> 6;
  const int wM   = (wv >> 1) * 64;
  const int wN   = (wv & 1) * 64;
  const int wMg  = wM >> 4;
  const int wNg  = wN >> 4;
  const int lr   = lane & 15;
  const int q    = lane >> 4;
  const int wr   = wv >> 1;
  const int wbase = wv * 64;           // wave-uniform

  const __bf16* Xb = Xc  + (size_t)bx * 32 * 4096;
  const __bf16* Zb = Wzc + (size_t)by * 32 * 4096;
  const __bf16* Hb = Whc + (size_t)by * 32 * 4096;

  f32x4 accz[4][4] = {};
  f32x4 acch[4][4] = {};

  for (int kblk = 0; kblk < 16; ++kblk) {   // BK=64: two 32-wide k-slices per iter
    __syncthreads();
    const size_t tb = (size_t)kblk * 8192;
    #pragma unroll
    for (int c = 0; c < 4; ++c) {
      const int eo = (c*256 + wbase + lane) * 8;  // per-lane global elem offset
      const int lo = (c*256 + wbase) * 8;         // wave-uniform LDS elem offset
      gload_lds16(Xb + tb + eo, As  + lo);
      gload_lds16(Zb + tb + eo, Bzs + lo);
      gload_lds16(Hb + tb + eo, Bhs + lo);
    }
    __syncthreads();

    #pragma unroll
    for (int h = 0; h < 2; ++h) {
      const int ho = h * 4096;                    // select k-slice within LDS
      bf16x8 af[4];
      #pragma unroll
      for (int i = 0; i < 4; ++i)
        af[i] = *(const bf16x8*)(As + ho + (wMg + i)*512 + lane*8);
      #pragma unroll
      for (int j = 0; j < 4; ++j) {
        bf16x8 bz8 = *(const bf16x8*)(Bzs + ho + (wNg + j)*512 + lane*8);
        bf16x8 bh8 = *(const bf16x8*)(Bhs + ho + (wNg + j)*512 + lane*8);
        #pragma unroll
        for (int i = 0; i < 4; ++i) {
          accz[j][i] = __builtin_amdgcn_mfma_f32_16x16x32_bf16(af[i], bz8, accz[j][i], 0, 0, 0);
          acch[j][i] = __builtin_amdgcn_mfma_f32_16x16x32_bf16(af[i], bh8, acch[j][i], 0, 0, 0);
        }
      }
    }
  }

  // ===================== fused scan epilogue =====================
  // C/D layout col=lane&15, row=(lane>>4)*4+reg (verified m89/m91).
  // CH=16 -> chunk_local = wr*4 + i (8 chunks per block of 128 rows).
  const int M0 = bx * 128, N0 = by * 128;
  const int cb = bx & ~(CPB-1);                 // chain base (sequence start)
  const int fidx = vbid;                        // spine slot == vbid

  __syncthreads();                              // K-loop LDS reads done; reuse As
  float* ldsA = (float*)As;                     // [8][128] chunk agg A
  float* ldsB = ldsA + 1024;                    // [8][128] chunk agg B
  float* hsL  = ldsB + 1024;                    // [8][128] chunk Hstart

  // ---- pass A: per-chunk aggregates + exclusive q-prefixes ----
  float EA[4][4], EB[4][4];
  #pragma unroll
  for (int j = 0; j < 4; ++j) {
    const int e = N0 + wN + j*16 + lr;
    const float bzv = bz[e];
    const float bhv = bh[e];
    #pragma unroll
    for (int i = 0; i < 4; ++i) {
      float A = 1.0f, Bv = 0.0f;
      #pragma unroll
      for (int r = 0; r < 4; ++r) {
        const float pz = accz[j][i][r] + bzv;
        const float ph = acch[j][i][r] + bhv;
        const float ex = __expf(-pz);
        const float z  = 1.0f / (1.0f + ex);
        const float af = fmaf(ex, z, 1e-8f);    // (1-z) + 1e-8, f32 throughout
        const float bf = z * ph;
        Bv = fmaf(af, Bv, bf);
        A *= af;
      }
      // inclusive scan across the 4 q-lane groups (stride 16)
      float sA = A, sB = Bv;
      #pragma unroll
      for (int s = 16; s < 64; s <<= 1) {
        const float Ap = __shfl_up(sA, s, 64);
        const float Bp = __shfl_up(sB, s, 64);
        if (lane >= s) { sB = fmaf(sA, Bp, sB); sA *= Ap; }
      }
      float eA = __shfl_up(sA, 16, 64);
      float eB = __shfl_up(sB, 16, 64);
      if (q == 0) { eA = 1.0f; eB = 0.0f; }
      EA[j][i] = eA; EB[j][i] = eB;
      // chunk aggregate lives at q==3; stash to LDS (one writer per d)
      const float cA = __shfl(sA, 48 + lr, 64);
      const float cB = __shfl(sB, 48 + lr, 64);
      if (q == 0) {
        ldsA[(wr*4 + i)*128 + (e - N0)] = cA;
        ldsB[(wr*4 + i)*128 + (e - N0)] = cB;
      }
    }
  }
  __syncthreads();

  // ---- spine: block aggregate publish (waves wr==1, q==0 lanes own 128 d) ----
  float bA[4], bB[4];
  if (wr == 1 && q == 0) {
    #pragma unroll
    for (int j = 0; j < 4; ++j) {
      const int dl = wN + j*16 + lr;
      float A = 1.0f, Bv = 0.0f;
      #pragma unroll
      for (int c = 0; c < 8; ++c) {             // compose 8 chunks in time order
        const float cA = ldsA[c*128 + dl];
        const float cB = ldsB[c*128 + dl];
        Bv = fmaf(cA, Bv, cB);
        A *= cA;
      }
      bA[j] = A; bB[j] = Bv;
      const size_t sidx = (size_t)fidx*128 + dl;
      __hip_atomic_store(&aggA[sidx], A,  __ATOMIC_RELAXED, __HIP_MEMORY_SCOPE_AGENT);
      __hip_atomic_store(&aggB[sidx], Bv, __ATOMIC_RELAXED, __HIP_MEMORY_SCOPE_AGENT);
    }
  }
  __syncthreads();                              // each wave drains its agg stores
  if (tid == 0)
    __hip_atomic_store(&ctrl[fidx], 1, __ATOMIC_RELEASE, __HIP_MEMORY_SCOPE_AGENT);

  // ---- lookback: exclusive block prefix per d; then chunk Hstarts ----
  // Spins only on vbids < fidx (same chain): those blocks took earlier
  // tickets => already executing => publish flag=1 with no upstream spin.
  if (wr == 1 && q == 0) {
    float Aex[4] = {1.f,1.f,1.f,1.f}, Bex[4] = {0.f,0.f,0.f,0.f};
    for (int k = fidx - 1; (k & 127) >= cb && (k & 127) != 127; --k) {
      int f;
      do {
        f = __hip_atomic_load(&ctrl[k], __ATOMIC_ACQUIRE, __HIP_MEMORY_SCOPE_AGENT);
        f = __builtin_amdgcn_readfirstlane(f);
        if (f == 0) __builtin_amdgcn_s_sleep(4);
      } while (f == 0);
      const float* pA = (f == 2) ? incA : aggA;
      const float* pB = (f == 2) ? incB : aggB;
      #pragma unroll
      for (int j = 0; j < 4; ++j) {
        const int dl = wN + j*16 + lr;
        const size_t sidx = (size_t)k*128 + dl;
        const float kA = __hip_atomic_load(&pA[sidx], __ATOMIC_RELAXED, __HIP_MEMORY_SCOPE_AGENT);
        const float kB = __hip_atomic_load(&pB[sidx], __ATOMIC_RELAXED, __HIP_MEMORY_SCOPE_AGENT);
        // cur (Aex,Bex) covers [k+1, bx-1]; prepend earlier segment k:
        Bex[j] = fmaf(Aex[j], kB, Bex[j]);
        Aex[j] *= kA;
      }
      if (f == 2) break;                        // composed a full inclusive prefix
    }
    #pragma unroll
    for (int j = 0; j < 4; ++j) {
      const int dl = wN + j*16 + lr;
      const size_t sidx = (size_t)fidx*128 + dl;
      // inclusive = own_agg o exclusive
      __hip_atomic_store(&incA[sidx], Aex[j]*bA[j],            __ATOMIC_RELAXED, __HIP_MEMORY_SCOPE_AGENT);
      __hip_atomic_store(&incB[sidx], fmaf(bA[j],Bex[j],bB[j]),__ATOMIC_RELAXED, __HIP_MEMORY_SCOPE_AGENT);
      // chunk Hstarts: h at block start = Bex (upstream applied to h0=0)
      float h = Bex[j];
      #pragma unroll
      for (int c = 0; c < 8; ++c) {
        hsL[c*128 + dl] = h;
        h = fmaf(ldsA[c*128 + dl], h, ldsB[c*128 + dl]);
      }
    }
  }
  __syncthreads();                              // inc + hsL drained/visible
  if (tid == 0)
    __hip_atomic_store(&ctrl[fidx], 2, __ATOMIC_RELEASE, __HIP_MEMORY_SCOPE_AGENT);

  // ---- pass B: recompute gate, apply prefix, write FINAL out ----
  #pragma unroll
  for (int j = 0; j < 4; ++j) {
    const int e = N0 + wN + j*16 + lr;
    const float bzv = bz[e];
    const float bhv = bh[e];
    #pragma unroll
    for (int i = 0; i < 4; ++i) {
      const int mbase = M0 + wM + i*16 + q*4;
      const float hs = hsL[(wr*4 + i)*128 + (e - N0)];
      float A = 1.0f, Bv = 0.0f;
      #pragma unroll
      for (int r = 0; r < 4; ++r) {
        const float pz = accz[j][i][r] + bzv;
        const float ph = acch[j][i][r] + bhv;
        const float ex = __expf(-pz);
        const float z  = 1.0f / (1.0f + ex);
        const float af = fmaf(ex, z, 1e-8f);
        const float bf = z * ph;
        Bv = fmaf(af, Bv, bf);
        A *= af;
        // within-chunk prefix at this row: Apre = A*EA, Bpre = A*EB + Bv
        const float Apre = A * EA[j][i];
        const float Bpre = fmaf(A, EB[j][i], Bv);
        out[(size_t)(mbase + r)*DSZ + e] = fmaf(Apre, hs, Bpre);
      }
    }
  }
}

extern "C" void kernel_launch(void* const* d_in, const int* in_sizes, int n_in,
                              void* d_out, int out_size, void* d_ws, size_t ws_size,
                              hipStream_t stream)
{
  const float* x  = (const float*)d_in[0];
  const float* Wz = (const float*)d_in[1];
  const float* bz = (const float*)d_in[2];
  const float* Wh = (const float*)d_in[3];
  const float* bh = (const float*)d_in[4];
  float* out = (float*)d_out;

  // ws: Xc (32MB) | Wzc (2MB) | Whc (2MB) | aggA/aggB/incA/incB (512KB ea) | ctrl (4KB+4)
  __bf16* Xc   = (__bf16*)d_ws;
  __bf16* Wzc  = Xc  + (size_t)MSZ * DSZ;
  __bf16* Whc  = Wzc + (size_t)DSZ * DSZ;
  float*  aggA = (float*)(Whc + (size_t)DSZ * DSZ);
  float*  aggB = aggA + (size_t)NBLK*128;
  float*  incA = aggB + (size_t)NBLK*128;
  float*  incB = incA + (size_t)NBLK*128;
  int*    ctrl = (int*)(incB + (size_t)NBLK*128);

  convert_tile_kernel<<<9216, 256, 0, stream>>>(x, Wz, Wh, Xc, Wzc, Whc, ctrl);
  gemm_scan_kernel<<<dim3(128, 8), 256, 0, stream>>>(
      Xc, Wzc, Whc, bz, bh, out, aggA, aggB, incA, incB, ctrl);
}

// Round 9
// 224.845 us; speedup vs baseline: 1.6450x; 1.6450x over previous
//
#include <hip/hip_runtime.h>
#include <hip/hip_bf16.h>

// MinGRU forward: z=sigmoid(xWz^T), h~=xWh^T, a=1-z+1e-8, b=z*h~, scan h=a*h+b.
// B=4 T=4096 D=1024.
// R12: fused GEMM+scan, spine made coherent via RMW-ONLY protocol.
// History: R10 (acquire/release spine) = CORRECT but acquire-per-poll emitted
// an L2 invalidate -> staged tiles evicted, MfmaUtil 31->10, 2.8x slow.
// R11 (relaxed spine) = WRONG: relaxed agent stores sit dirty in the producer
// XCD's write-back L2; flag line can evict (become visible) before payload
// lines -> consumer reads stale payload. Fix: EVERY spine access is an atomic
// RMW (exchange for writes, fetch_add(0) for reads/polls) -- RMWs execute at
// the coherence point regardless of cache state (same mechanism as the ticket
// fetch_add, which worked in all rounds). No buffer_inv ever; no spine line
// is ever cached. Ordering: __syncthreads' implicit vmcnt(0) drains payload
// RMWs (ack from coherence point) before the flag RMW issues; consumer's
// payload RMW reads are control-dependent on the observed flag.
// Everything else identical to R11 (K-loop = verified R8 structure, BK=64
// dual-acc; by-fastest vbid mapping keeps weights L2-hot; ticket-ordered
// vbid => lookback spins only on already-started blocks => deadlock-free).

typedef __bf16 bf16x8 __attribute__((ext_vector_type(8)));
typedef float  f32x4  __attribute__((ext_vector_type(4)));

#define BSZ 4
#define TSZ 4096
#define DSZ 1024
#define MSZ (BSZ*TSZ)      // 16384 rows
#define CH  16             // scan chunk length
#define NC  (TSZ/CH)       // 256 chunks per sequence
#define CPB 32             // chain length in blocks (4096 rows / 128)
#define NBLK 1024          // total gemm blocks (128 x-tiles * 8 y-tiles)

__device__ __forceinline__ void gload_lds16(const __bf16* g, __bf16* l) {
  __builtin_amdgcn_global_load_lds(
      (const __attribute__((address_space(1))) void*)g,
      (__attribute__((address_space(3))) void*)l, 16, 0, 0);
}

// ---- spine access: RMW-only (executes at coherence point, no cache ops) ----
__device__ __forceinline__ void  spineWr(float* p, float v) {
  (void)__hip_atomic_exchange(p, v, __ATOMIC_RELAXED, __HIP_MEMORY_SCOPE_AGENT);
}
__device__ __forceinline__ float spineRd(float* p) {
  return __hip_atomic_fetch_add(p, 0.0f, __ATOMIC_RELAXED, __HIP_MEMORY_SCOPE_AGENT);
}
__device__ __forceinline__ void  flagWr(int* p, int v) {
  (void)__hip_atomic_exchange(p, v, __ATOMIC_RELAXED, __HIP_MEMORY_SCOPE_AGENT);
}
__device__ __forceinline__ int   flagRd(int* p) {
  return __hip_atomic_fetch_add(p, 0, __ATOMIC_RELAXED, __HIP_MEMORY_SCOPE_AGENT);
}

// ---------------- conversion: fp32 row-major -> bf16 fragment-tiled ----------------
// tiled layout: [rowblk][kblk:32][i:8][l:64][j:8] where
//   row = rowblk*128 + i*16 + (l&15), k = kblk*32 + (l>>4)*8 + j
// Block 0 zeroes spine flags + ticket; end-of-kernel implicit release makes
// the zeroing visible to gemm_scan's coherence-point RMWs.
__global__ void convert_tile_kernel(const float* __restrict__ X,
                                    const float* __restrict__ Wz,
                                    const float* __restrict__ Wh,
                                    __bf16* __restrict__ Xc,
                                    __bf16* __restrict__ Wzc,
                                    __bf16* __restrict__ Whc,
                                    int* __restrict__ ctrl)
{
  const int bx = blockIdx.x;
  if (bx == 0) {
    #pragma unroll
    for (int k = 0; k < 4; ++k) ctrl[k*256 + threadIdx.x] = 0;
    if (threadIdx.x == 0) ctrl[NBLK] = 0;      // ticket
  }
  const float* src; __bf16* dst; int gid;
  if (bx < 8192)      { src = X;  dst = Xc;  gid =  bx        *256 + threadIdx.x; }
  else if (bx < 8704) { src = Wz; dst = Wzc; gid = (bx - 8192)*256 + threadIdx.x; }
  else                { src = Wh; dst = Whc; gid = (bx - 8704)*256 + threadIdx.x; }
  const int l    = gid & 63;
  const int i    = (gid >> 6) & 7;
  const int kblk = (gid >> 9) & 31;
  const int rblk = gid >> 14;
  const int row  = rblk*128 + i*16 + (l & 15);
  const int col  = kblk*32 + (l >> 4)*8;
  const float* g = src + (size_t)row*DSZ + col;
  float4 v0 = *(const float4*)g;
  float4 v1 = *(const float4*)(g + 4);
  bf16x8 p;
  p[0]=(__bf16)v0.x; p[1]=(__bf16)v0.y; p[2]=(__bf16)v0.z; p[3]=(__bf16)v0.w;
  p[4]=(__bf16)v1.x; p[5]=(__bf16)v1.y; p[6]=(__bf16)v1.z; p[7]=(__bf16)v1.w;
  *(bf16x8*)(dst + (size_t)gid*8) = p;
}

// ---------------- fused GEMM + gate + full scan + final output ----------------
// block tile 128(M) x 128(N), BK=64; 256 threads = 4 waves in 2x2, each 64x64.
__global__ __launch_bounds__(256, 2) void gemm_scan_kernel(
    const __bf16* __restrict__ Xc,  const __bf16* __restrict__ Wzc,
    const __bf16* __restrict__ Whc,
    const float* __restrict__ bz, const float* __restrict__ bh,
    float* __restrict__ out,
    float* aggA, float* aggB, float* incA, float* incB, int* ctrl)
{
  __shared__ __align__(16) __bf16 As [8192];
  __shared__ __align__(16) __bf16 Bzs[8192];
  __shared__ __align__(16) __bf16 Bhs[8192];
  __shared__ int vbid_s;

  const int tid  = threadIdx.x;
  // ---- ticket: dispatch-order-independent chain position ----
  if (tid == 0)
    vbid_s = __hip_atomic_fetch_add(&ctrl[NBLK], 1, __ATOMIC_RELAXED,
                                    __HIP_MEMORY_SCOPE_AGENT) & (NBLK - 1);
  __syncthreads();
  const int vbid = vbid_s;
  const int bx = vbid >> 3;            // M tile (chain position); x-major
  const int by = vbid & 7;             // N tile (fastest -> X-tile reuse, weights L2-hot)

  const int lane = tid & 63;
  const int wv   = tid >> 6;
  const int wM   = (wv >> 1) * 64;
  const int wN   = (wv & 1) * 64;
  const int wMg  = wM >> 4;
  const int wNg  = wN >> 4;
  const int lr   = lane & 15;
  const int q    = lane >> 4;
  const int wr   = wv >> 1;
  const int wbase = wv * 64;           // wave-uniform

  const __bf16* Xb = Xc  + (size_t)bx * 32 * 4096;
  const __bf16* Zb = Wzc + (size_t)by * 32 * 4096;
  const __bf16* Hb = Whc + (size_t)by * 32 * 4096;

  f32x4 accz[4][4] = {};
  f32x4 acch[4][4] = {};

  for (int kblk = 0; kblk < 16; ++kblk) {   // BK=64: two 32-wide k-slices per iter
    __syncthreads();
    const size_t tb = (size_t)kblk * 8192;
    #pragma unroll
    for (int c = 0; c < 4; ++c) {
      const int eo = (c*256 + wbase + lane) * 8;  // per-lane global elem offset
      const int lo = (c*256 + wbase) * 8;         // wave-uniform LDS elem offset
      gload_lds16(Xb + tb + eo, As  + lo);
      gload_lds16(Zb + tb + eo, Bzs + lo);
      gload_lds16(Hb + tb + eo, Bhs + lo);
    }
    __syncthreads();

    #pragma unroll
    for (int h = 0; h < 2; ++h) {
      const int ho = h * 4096;                    // select k-slice within LDS
      bf16x8 af[4];
      #pragma unroll
      for (int i = 0; i < 4; ++i)
        af[i] = *(const bf16x8*)(As + ho + (wMg + i)*512 + lane*8);
      #pragma unroll
      for (int j = 0; j < 4; ++j) {
        bf16x8 bz8 = *(const bf16x8*)(Bzs + ho + (wNg + j)*512 + lane*8);
        bf16x8 bh8 = *(const bf16x8*)(Bhs + ho + (wNg + j)*512 + lane*8);
        #pragma unroll
        for (int i = 0; i < 4; ++i) {
          accz[j][i] = __builtin_amdgcn_mfma_f32_16x16x32_bf16(af[i], bz8, accz[j][i], 0, 0, 0);
          acch[j][i] = __builtin_amdgcn_mfma_f32_16x16x32_bf16(af[i], bh8, acch[j][i], 0, 0, 0);
        }
      }
    }
  }

  // ===================== fused scan epilogue =====================
  // C/D layout col=lane&15, row=(lane>>4)*4+reg (verified m89/m91).
  // CH=16 -> chunk_local = wr*4 + i (8 chunks per block of 128 rows).
  const int M0 = bx * 128, N0 = by * 128;
  const int cb = bx & ~(CPB-1);                 // chain base (sequence start)
  const int fidx = vbid;                        // spine slot == vbid

  __syncthreads();                              // K-loop LDS reads done; reuse As
  float* ldsA = (float*)As;                     // [8][128] chunk agg A
  float* ldsB = ldsA + 1024;                    // [8][128] chunk agg B
  float* hsL  = ldsB + 1024;                    // [8][128] chunk Hstart

  // ---- pass A: per-chunk aggregates + exclusive q-prefixes ----
  float EA[4][4], EB[4][4];
  #pragma unroll
  for (int j = 0; j < 4; ++j) {
    const int e = N0 + wN + j*16 + lr;
    const float bzv = bz[e];
    const float bhv = bh[e];
    #pragma unroll
    for (int i = 0; i < 4; ++i) {
      float A = 1.0f, Bv = 0.0f;
      #pragma unroll
      for (int r = 0; r < 4; ++r) {
        const float pz = accz[j][i][r] + bzv;
        const float ph = acch[j][i][r] + bhv;
        const float ex = __expf(-pz);
        const float z  = 1.0f / (1.0f + ex);
        const float af = fmaf(ex, z, 1e-8f);    // (1-z) + 1e-8, f32 throughout
        const float bf = z * ph;
        Bv = fmaf(af, Bv, bf);
        A *= af;
      }
      // inclusive scan across the 4 q-lane groups (stride 16)
      float sA = A, sB = Bv;
      #pragma unroll
      for (int s = 16; s < 64; s <<= 1) {
        const float Ap = __shfl_up(sA, s, 64);
        const float Bp = __shfl_up(sB, s, 64);
        if (lane >= s) { sB = fmaf(sA, Bp, sB); sA *= Ap; }
      }
      float eA = __shfl_up(sA, 16, 64);
      float eB = __shfl_up(sB, 16, 64);
      if (q == 0) { eA = 1.0f; eB = 0.0f; }
      EA[j][i] = eA; EB[j][i] = eB;
      // chunk aggregate lives at q==3; stash to LDS (one writer per d)
      const float cA = __shfl(sA, 48 + lr, 64);
      const float cB = __shfl(sB, 48 + lr, 64);
      if (q == 0) {
        ldsA[(wr*4 + i)*128 + (e - N0)] = cA;
        ldsB[(wr*4 + i)*128 + (e - N0)] = cB;
      }
    }
  }
  __syncthreads();

  // ---- spine: block aggregate publish (waves wr==1, q==0 lanes own 128 d) ----
  float bA[4], bB[4];
  if (wr == 1 && q == 0) {
    #pragma unroll
    for (int j = 0; j < 4; ++j) {
      const int dl = wN + j*16 + lr;
      float A = 1.0f, Bv = 0.0f;
      #pragma unroll
      for (int c = 0; c < 8; ++c) {             // compose 8 chunks in time order
        const float cA = ldsA[c*128 + dl];
        const float cB = ldsB[c*128 + dl];
        Bv = fmaf(cA, Bv, cB);
        A *= cA;
      }
      bA[j] = A; bB[j] = Bv;
      const size_t sidx = (size_t)fidx*128 + dl;
      spineWr(&aggA[sidx], A);
      spineWr(&aggB[sidx], Bv);
    }
  }
  __syncthreads();   // implicit vmcnt(0): payload RMWs acked at coherence point
  if (tid == 0) flagWr(&ctrl[fidx], 1);

  // ---- lookback: exclusive block prefix per d; then chunk Hstarts ----
  // Spins only on lower-vbid blocks (earlier tickets => already executing =>
  // publish flag=1 with no upstream spin) -> deadlock-free under any dispatch.
  if (wr == 1 && q == 0) {
    float Aex[4] = {1.f,1.f,1.f,1.f}, Bex[4] = {0.f,0.f,0.f,0.f};
    for (int kx = bx - 1; kx >= cb; --kx) {
      const int k = kx*8 + by;                  // spine slot of predecessor
      int f;
      do {
        f = flagRd(&ctrl[k]);
        f = __builtin_amdgcn_readfirstlane(f);
        if (f == 0) __builtin_amdgcn_s_sleep(16);
      } while (f == 0);
      float* pA = (f == 2) ? incA : aggA;
      float* pB = (f == 2) ? incB : aggB;
      #pragma unroll
      for (int j = 0; j < 4; ++j) {
        const int dl = wN + j*16 + lr;
        const size_t sidx = (size_t)k*128 + dl;
        const float kA = spineRd(&pA[sidx]);
        const float kB = spineRd(&pB[sidx]);
        // cur (Aex,Bex) covers [kx+1, bx-1]; prepend earlier segment kx:
        Bex[j] = fmaf(Aex[j], kB, Bex[j]);
        Aex[j] *= kA;
      }
      if (f == 2) break;                        // composed a full inclusive prefix
    }
    #pragma unroll
    for (int j = 0; j < 4; ++j) {
      const int dl = wN + j*16 + lr;
      const size_t sidx = (size_t)fidx*128 + dl;
      // inclusive = own_agg o exclusive
      spineWr(&incA[sidx], Aex[j]*bA[j]);
      spineWr(&incB[sidx], fmaf(bA[j], Bex[j], bB[j]));
      // chunk Hstarts: h at block start = Bex (upstream applied to h0=0)
      float h = Bex[j];
      #pragma unroll
      for (int c = 0; c < 8; ++c) {
        hsL[c*128 + dl] = h;
        h = fmaf(ldsA[c*128 + dl], h, ldsB[c*128 + dl]);
      }
    }
  }
  __syncthreads();   // implicit vmcnt(0): inc RMWs acked; hsL visible
  if (tid == 0) flagWr(&ctrl[fidx], 2);

  // ---- pass B: recompute gate, apply prefix, write FINAL out ----
  #pragma unroll
  for (int j = 0; j < 4; ++j) {
    const int e = N0 + wN + j*16 + lr;
    const float bzv = bz[e];
    const float bhv = bh[e];
    #pragma unroll
    for (int i = 0; i < 4; ++i) {
      const int mbase = M0 + wM + i*16 + q*4;
      const float hs = hsL[(wr*4 + i)*128 + (e - N0)];
      float A = 1.0f, Bv = 0.0f;
      #pragma unroll
      for (int r = 0; r < 4; ++r) {
        const float pz = accz[j][i][r] + bzv;
        const float ph = acch[j][i][r] + bhv;
        const float ex = __expf(-pz);
        const float z  = 1.0f / (1.0f + ex);
        const float af = fmaf(ex, z, 1e-8f);
        const float bf = z * ph;
        Bv = fmaf(af, Bv, bf);
        A *= af;
        // within-chunk prefix at this row: Apre = A*EA, Bpre = A*EB + Bv
        const float Apre = A * EA[j][i];
        const float Bpre = fmaf(A, EB[j][i], Bv);
        out[(size_t)(mbase + r)*DSZ + e] = fmaf(Apre, hs, Bpre);
      }
    }
  }
}

extern "C" void kernel_launch(void* const* d_in, const int* in_sizes, int n_in,
                              void* d_out, int out_size, void* d_ws, size_t ws_size,
                              hipStream_t stream)
{
  const float* x  = (const float*)d_in[0];
  const float* Wz = (const float*)d_in[1];
  const float* bz = (const float*)d_in[2];
  const float* Wh = (const float*)d_in[3];
  const float* bh = (const float*)d_in[4];
  float* out = (float*)d_out;

  // ws: Xc (32MB) | Wzc (2MB) | Whc (2MB) | aggA/aggB/incA/incB (512KB ea) | ctrl (4KB+4)
  __bf16* Xc   = (__bf16*)d_ws;
  __bf16* Wzc  = Xc  + (size_t)MSZ * DSZ;
  __bf16* Whc  = Wzc + (size_t)DSZ * DSZ;
  float*  aggA = (float*)(Whc + (size_t)DSZ * DSZ);
  float*  aggB = aggA + (size_t)NBLK*128;
  float*  incA = aggB + (size_t)NBLK*128;
  float*  incB = incA + (size_t)NBLK*128;
  int*    ctrl = (int*)(incB + (size_t)NBLK*128);

  convert_tile_kernel<<<9216, 256, 0, stream>>>(x, Wz, Wh, Xc, Wzc, Whc, ctrl);
  gemm_scan_kernel<<<dim3(128, 8), 256, 0, stream>>>(
      Xc, Wzc, Whc, bz, bh, out, aggA, aggB, incA, incB, ctrl);
}